// Round 1
// baseline (2859.146 us; speedup 1.0000x reference)
//
#include <hip/hip_runtime.h>

#define NNODES 50000
#define CIN 128
#define HCH 128
#define NEG 0.01f
#define BN_EPS 1e-5f

#define NB 32          // nodes per block in fused_mlp
#define KC 16          // k-chunk for weights
#define RW 20          // LDS row pitch for weight chunks (16 + 4)
#define RF 132         // LDS row pitch for features (128 + 4)

__device__ __forceinline__ float lrelu(float v) { return v >= 0.f ? v : NEG * v; }

// ---------------- scatter-add: agg[dst] += x[src] ----------------
__global__ __launch_bounds__(256)
void scatter_add_kernel(const float4* __restrict__ x4, const int* __restrict__ src,
                        const int* __restrict__ dst, float* __restrict__ agg, int n_edges)
{
    int t = blockIdx.x * 256 + threadIdx.x;
    int e = t >> 5;          // 32 threads per edge
    int c = t & 31;          // float4 lane within the 128-ch row
    if (e >= n_edges) return;
    int s = src[e];
    int d = dst[e];
    float4 v = x4[(long)s * 32 + c];
    float* ap = agg + (long)d * 128 + c * 4;
    atomicAdd(ap + 0, v.x);
    atomicAdd(ap + 1, v.y);
    atomicAdd(ap + 2, v.z);
    atomicAdd(ap + 3, v.w);
}

// ---------------- fused 2x GEMM + leaky + BN partial stats ----------------
// x1 = agg@Wrel^T + brel + x@Wroot^T ; x2 = lrelu(x1) ; x3 = x2@Wlin^T + blin
// x3 -> d_out (later normalized in place). Per-block BN partial sums -> atomics.
__global__ __launch_bounds__(256)
void fused_mlp_kernel(const float* __restrict__ agg, const float* __restrict__ x,
                      const float* __restrict__ Wrel, const float* __restrict__ brel,
                      const float* __restrict__ Wroot, const float* __restrict__ Wlin,
                      const float* __restrict__ blin,
                      float* __restrict__ x3out, float* __restrict__ sums,
                      float* __restrict__ sumsq)
{
    __shared__ __align__(16) float smA[NB][RF];     // agg rows, later x2 [n][h]
    __shared__ __align__(16) float smX[NB][RF];     // x rows, later x3 [n][h]
    __shared__ __align__(16) float smW0[HCH][RW];   // Wrel / Wlin chunk
    __shared__ __align__(16) float smW1[HCH][RW];   // Wroot chunk

    const int tid = threadIdx.x;
    const int tn = tid & 7;     // node sub-index: owns nodes tn + 8*ni
    const int th = tid >> 3;    // 0..31: owns channels th + 32*hi
    const int n0 = blockIdx.x * NB;

    // ---- stage features into LDS (float4, coalesced) ----
    {
        const float4* a4 = (const float4*)agg;
        const float4* x4 = (const float4*)x;
        #pragma unroll
        for (int i = 0; i < 4; ++i) {
            int e = tid + i * 256;          // 1024 float4s = 32 x 128 floats
            int n = e >> 5, kq = e & 31;
            float4 va = make_float4(0.f, 0.f, 0.f, 0.f);
            float4 vx = va;
            if (n0 + n < NNODES) {
                va = a4[(long)(n0 + n) * 32 + kq];
                vx = x4[(long)(n0 + n) * 32 + kq];
            }
            *(float4*)&smA[n][kq * 4] = va;
            *(float4*)&smX[n][kq * 4] = vx;
        }
    }

    float acc[4][4];
    #pragma unroll
    for (int i = 0; i < 4; ++i)
        #pragma unroll
        for (int j = 0; j < 4; ++j) acc[i][j] = 0.f;

    // ---- stage 1: acc = agg@Wrel^T + x@Wroot^T ----
    for (int kc = 0; kc < CIN; kc += KC) {
        __syncthreads();   // also covers the feature staging on first iter
        #pragma unroll
        for (int i = 0; i < 8; ++i) {       // 2048 floats per matrix
            int e = tid + i * 256;
            int row = e >> 4, col = e & 15;
            smW0[row][col] = Wrel[row * 128 + kc + col];
            smW1[row][col] = Wroot[row * 128 + kc + col];
        }
        __syncthreads();
        #pragma unroll
        for (int kq = 0; kq < KC / 4; ++kq) {
            float4 wr[4], wo[4], fa[4], fx[4];
            #pragma unroll
            for (int hi = 0; hi < 4; ++hi) {
                wr[hi] = *(const float4*)&smW0[th + 32 * hi][kq * 4];
                wo[hi] = *(const float4*)&smW1[th + 32 * hi][kq * 4];
            }
            #pragma unroll
            for (int ni = 0; ni < 4; ++ni) {
                fa[ni] = *(const float4*)&smA[tn + 8 * ni][kc + kq * 4];
                fx[ni] = *(const float4*)&smX[tn + 8 * ni][kc + kq * 4];
            }
            #pragma unroll
            for (int ni = 0; ni < 4; ++ni)
                #pragma unroll
                for (int hi = 0; hi < 4; ++hi) {
                    acc[ni][hi] += fa[ni].x * wr[hi].x + fa[ni].y * wr[hi].y
                                 + fa[ni].z * wr[hi].z + fa[ni].w * wr[hi].w
                                 + fx[ni].x * wo[hi].x + fx[ni].y * wo[hi].y
                                 + fx[ni].z * wo[hi].z + fx[ni].w * wo[hi].w;
                }
        }
    }

    // ---- x2 = lrelu(acc + brel) -> smA[n][h] ----
    __syncthreads();
    #pragma unroll
    for (int hi = 0; hi < 4; ++hi) {
        float b = brel[th + 32 * hi];
        #pragma unroll
        for (int ni = 0; ni < 4; ++ni)
            smA[tn + 8 * ni][th + 32 * hi] = lrelu(acc[ni][hi] + b);
    }

    // ---- stage 2: acc2 = x2@Wlin^T ----
    float acc2[4][4];
    #pragma unroll
    for (int i = 0; i < 4; ++i)
        #pragma unroll
        for (int j = 0; j < 4; ++j) acc2[i][j] = 0.f;

    for (int kc = 0; kc < HCH; kc += KC) {
        __syncthreads();
        #pragma unroll
        for (int i = 0; i < 8; ++i) {
            int e = tid + i * 256;
            int row = e >> 4, col = e & 15;
            smW0[row][col] = Wlin[row * 128 + kc + col];
        }
        __syncthreads();
        #pragma unroll
        for (int kq = 0; kq < KC / 4; ++kq) {
            float4 wl[4], f2[4];
            #pragma unroll
            for (int hi = 0; hi < 4; ++hi)
                wl[hi] = *(const float4*)&smW0[th + 32 * hi][kq * 4];
            #pragma unroll
            for (int ni = 0; ni < 4; ++ni)
                f2[ni] = *(const float4*)&smA[tn + 8 * ni][kc + kq * 4];
            #pragma unroll
            for (int ni = 0; ni < 4; ++ni)
                #pragma unroll
                for (int hi = 0; hi < 4; ++hi)
                    acc2[ni][hi] += f2[ni].x * wl[hi].x + f2[ni].y * wl[hi].y
                                  + f2[ni].z * wl[hi].z + f2[ni].w * wl[hi].w;
        }
    }

    // ---- x3 = acc2 + blin -> smX; BN partial sums ----
    __syncthreads();
    bool valid[4];
    #pragma unroll
    for (int ni = 0; ni < 4; ++ni) valid[ni] = (n0 + tn + 8 * ni) < NNODES;

    #pragma unroll
    for (int hi = 0; hi < 4; ++hi) {
        float b = blin[th + 32 * hi];
        float ps = 0.f, pq = 0.f;
        #pragma unroll
        for (int ni = 0; ni < 4; ++ni) {
            float v = acc2[ni][hi] + b;
            smX[tn + 8 * ni][th + 32 * hi] = v;
            if (valid[ni]) { ps += v; pq += v * v; }
        }
        // reduce over the 8 tn lanes (consecutive lanes share th)
        ps += __shfl_xor(ps, 1); ps += __shfl_xor(ps, 2); ps += __shfl_xor(ps, 4);
        pq += __shfl_xor(pq, 1); pq += __shfl_xor(pq, 2); pq += __shfl_xor(pq, 4);
        if (tn == 0) {
            atomicAdd(&sums[th + 32 * hi], ps);
            atomicAdd(&sumsq[th + 32 * hi], pq);
        }
    }
    __syncthreads();

    // ---- coalesced x3 store ----
    #pragma unroll
    for (int i = 0; i < 4; ++i) {
        int e = tid + i * 256;
        int n = e >> 5, kq = e & 31;
        if (n0 + n < NNODES)
            ((float4*)x3out)[(long)(n0 + n) * 32 + kq] = *(const float4*)&smX[n][kq * 4];
    }
}

// ---------------- BN finalize: scale/shift ----------------
__global__ void bn_final_kernel(const float* __restrict__ sums, const float* __restrict__ sumsq,
                                const float* __restrict__ gamma, const float* __restrict__ beta,
                                float* __restrict__ ss)
{
    int h = threadIdx.x;
    float mean = sums[h] * (1.f / NNODES);
    float var = sumsq[h] * (1.f / NNODES) - mean * mean;
    float sc = gamma[h] * rsqrtf(var + BN_EPS);
    ss[h] = sc;
    ss[128 + h] = beta[h] - mean * sc;
}

// ---------------- BN apply + leaky (in-place on d_out) ----------------
__global__ __launch_bounds__(256)
void bn_apply_kernel(float* __restrict__ out, const float* __restrict__ ss)
{
    __shared__ float s_sc[128], s_sh[128];
    if (threadIdx.x < 128) {
        s_sc[threadIdx.x] = ss[threadIdx.x];
        s_sh[threadIdx.x] = ss[128 + threadIdx.x];
    }
    __syncthreads();
    const int total = NNODES * 32;   // float4 count
    float4* o4 = (float4*)out;
    for (int i = blockIdx.x * 256 + threadIdx.x; i < total; i += gridDim.x * 256) {
        float4 v = o4[i];
        int h = (i & 31) * 4;
        v.x = lrelu(v.x * s_sc[h + 0] + s_sh[h + 0]);
        v.y = lrelu(v.y * s_sc[h + 1] + s_sh[h + 1]);
        v.z = lrelu(v.z * s_sc[h + 2] + s_sh[h + 2]);
        v.w = lrelu(v.w * s_sc[h + 3] + s_sh[h + 3]);
        o4[i] = v;
    }
}

extern "C" void kernel_launch(void* const* d_in, const int* in_sizes, int n_in,
                              void* d_out, int out_size, void* d_ws, size_t ws_size,
                              hipStream_t stream)
{
    const float* x     = (const float*)d_in[0];
    const int*   ei    = (const int*)d_in[1];
    // d_in[2] = batch (unused: single graph)
    const float* Wrel  = (const float*)d_in[3];
    const float* brel  = (const float*)d_in[4];
    const float* Wroot = (const float*)d_in[5];
    const float* Wlin  = (const float*)d_in[6];
    const float* blin  = (const float*)d_in[7];
    const float* gamma = (const float*)d_in[8];
    const float* beta  = (const float*)d_in[9];
    float* out = (float*)d_out;

    const int n_edges = in_sizes[1] / 2;
    const int* src = ei;
    const int* dst = ei + n_edges;

    char* ws = (char*)d_ws;
    float* agg   = (float*)ws;                          // 50000*128*4 = 25.6 MB
    float* sums  = (float*)(ws + 25600000);             // 128 f
    float* sumsq = sums + 128;                          // 128 f
    float* ss    = sums + 256;                          // 256 f (scale | shift)

    // zero agg + stats
    hipMemsetAsync(agg, 0, 25600000 + 2048, stream);

    {
        long threads = (long)n_edges * 32;
        int blocks = (int)((threads + 255) / 256);
        scatter_add_kernel<<<blocks, 256, 0, stream>>>((const float4*)x, src, dst, agg, n_edges);
    }

    fused_mlp_kernel<<<(NNODES + NB - 1) / NB, 256, 0, stream>>>(
        agg, x, Wrel, brel, Wroot, Wlin, blin, out, sums, sumsq);

    bn_final_kernel<<<1, 128, 0, stream>>>(sums, sumsq, gamma, beta, ss);

    bn_apply_kernel<<<2048, 256, 0, stream>>>(out, ss);
}

// Round 2
// 592.195 us; speedup vs baseline: 4.8280x; 4.8280x over previous
//
#include <hip/hip_runtime.h>

#define NNODES 50000
#define CIN 128
#define HCH 128
#define NEG 0.01f
#define BN_EPS 1e-5f

#define NB 32          // nodes per block in fused_mlp
#define KC 16          // k-chunk for weights
#define RW 20          // LDS row pitch for weight chunks (16 + 4)
#define RF 132         // LDS row pitch for features (128 + 4)

__device__ __forceinline__ float lrelu(float v) { return v >= 0.f ? v : NEG * v; }

// ---------------- 1. histogram: cnt[dst]++ ----------------
__global__ __launch_bounds__(256)
void hist_kernel(const int* __restrict__ dst, int* __restrict__ cnt, int n_edges)
{
    for (int i = blockIdx.x * 256 + threadIdx.x; i < n_edges; i += gridDim.x * 256)
        atomicAdd(&cnt[dst[i]], 1);
}

// ---------------- 2. exclusive scan over 50k counts (1 block) ----------------
__global__ __launch_bounds__(256)
void scan_kernel(const int* __restrict__ cnt, int* __restrict__ offs, int* __restrict__ cur)
{
    __shared__ int wsum[4];
    const int t = threadIdx.x;
    const int per = (NNODES + 255) / 256;             // 196
    const int begin = t * per;
    const int end = min(begin + per, NNODES);

    int s = 0;
    for (int i = begin; i < end; ++i) s += cnt[i];

    // inclusive scan of per-thread sums: wave shfl + cross-wave LDS
    const int lane = t & 63, w = t >> 6;
    int v = s;
    #pragma unroll
    for (int d = 1; d < 64; d <<= 1) {
        int u = __shfl_up(v, d);
        if (lane >= d) v += u;
    }
    if (lane == 63) wsum[w] = v;
    __syncthreads();
    int woff = 0;
    for (int i = 0; i < w; ++i) woff += wsum[i];
    int run = woff + v - s;                            // exclusive prefix

    for (int i = begin; i < end; ++i) {
        offs[i] = run; cur[i] = run;
        run += cnt[i];
    }
    if (t == 255) offs[NNODES] = run;                  // = n_edges
}

// ---------------- 3. bucket edges by dst ----------------
__global__ __launch_bounds__(256)
void bucket_kernel(const int* __restrict__ src, const int* __restrict__ dst,
                   int* __restrict__ cur, int* __restrict__ esrc, int n_edges)
{
    for (int i = blockIdx.x * 256 + threadIdx.x; i < n_edges; i += gridDim.x * 256) {
        int p = atomicAdd(&cur[dst[i]], 1);
        esrc[p] = src[i];
    }
}

// ---------------- 4. gather-accumulate: agg[n] = sum x[esrc] ----------------
__global__ __launch_bounds__(256)
void gather_kernel(const float4* __restrict__ x4, const int* __restrict__ esrc,
                   const int* __restrict__ offs, float4* __restrict__ agg4)
{
    const int g = blockIdx.x * 8 + (threadIdx.x >> 5);   // node
    const int lane = threadIdx.x & 31;                   // float4 lane in row
    if (g >= NNODES) return;
    const int b = offs[g], e = offs[g + 1];

    float4 a0 = make_float4(0.f, 0.f, 0.f, 0.f);
    float4 a1 = a0;
    int i = b;
    for (; i + 1 < e; i += 2) {
        int s0 = esrc[i], s1 = esrc[i + 1];
        float4 v0 = x4[(long)s0 * 32 + lane];
        float4 v1 = x4[(long)s1 * 32 + lane];
        a0.x += v0.x; a0.y += v0.y; a0.z += v0.z; a0.w += v0.w;
        a1.x += v1.x; a1.y += v1.y; a1.z += v1.z; a1.w += v1.w;
    }
    if (i < e) {
        int s0 = esrc[i];
        float4 v0 = x4[(long)s0 * 32 + lane];
        a0.x += v0.x; a0.y += v0.y; a0.z += v0.z; a0.w += v0.w;
    }
    a0.x += a1.x; a0.y += a1.y; a0.z += a1.z; a0.w += a1.w;
    agg4[(long)g * 32 + lane] = a0;
}

// ---------------- fused 2x GEMM + leaky + BN partial stats ----------------
__global__ __launch_bounds__(256)
void fused_mlp_kernel(const float* __restrict__ agg, const float* __restrict__ x,
                      const float* __restrict__ Wrel, const float* __restrict__ brel,
                      const float* __restrict__ Wroot, const float* __restrict__ Wlin,
                      const float* __restrict__ blin,
                      float* __restrict__ x3out, float* __restrict__ sums,
                      float* __restrict__ sumsq)
{
    __shared__ __align__(16) float smA[NB][RF];     // agg rows, later x2 [n][h]
    __shared__ __align__(16) float smX[NB][RF];     // x rows, later x3 [n][h]
    __shared__ __align__(16) float smW0[HCH][RW];   // Wrel / Wlin chunk
    __shared__ __align__(16) float smW1[HCH][RW];   // Wroot chunk

    const int tid = threadIdx.x;
    const int tn = tid & 7;     // node sub-index: owns nodes tn + 8*ni
    const int th = tid >> 3;    // 0..31: owns channels th + 32*hi
    const int n0 = blockIdx.x * NB;

    {
        const float4* a4 = (const float4*)agg;
        const float4* x4 = (const float4*)x;
        #pragma unroll
        for (int i = 0; i < 4; ++i) {
            int e = tid + i * 256;
            int n = e >> 5, kq = e & 31;
            float4 va = make_float4(0.f, 0.f, 0.f, 0.f);
            float4 vx = va;
            if (n0 + n < NNODES) {
                va = a4[(long)(n0 + n) * 32 + kq];
                vx = x4[(long)(n0 + n) * 32 + kq];
            }
            *(float4*)&smA[n][kq * 4] = va;
            *(float4*)&smX[n][kq * 4] = vx;
        }
    }

    float acc[4][4];
    #pragma unroll
    for (int i = 0; i < 4; ++i)
        #pragma unroll
        for (int j = 0; j < 4; ++j) acc[i][j] = 0.f;

    for (int kc = 0; kc < CIN; kc += KC) {
        __syncthreads();
        #pragma unroll
        for (int i = 0; i < 8; ++i) {
            int e = tid + i * 256;
            int row = e >> 4, col = e & 15;
            smW0[row][col] = Wrel[row * 128 + kc + col];
            smW1[row][col] = Wroot[row * 128 + kc + col];
        }
        __syncthreads();
        #pragma unroll
        for (int kq = 0; kq < KC / 4; ++kq) {
            float4 wr[4], wo[4], fa[4], fx[4];
            #pragma unroll
            for (int hi = 0; hi < 4; ++hi) {
                wr[hi] = *(const float4*)&smW0[th + 32 * hi][kq * 4];
                wo[hi] = *(const float4*)&smW1[th + 32 * hi][kq * 4];
            }
            #pragma unroll
            for (int ni = 0; ni < 4; ++ni) {
                fa[ni] = *(const float4*)&smA[tn + 8 * ni][kc + kq * 4];
                fx[ni] = *(const float4*)&smX[tn + 8 * ni][kc + kq * 4];
            }
            #pragma unroll
            for (int ni = 0; ni < 4; ++ni)
                #pragma unroll
                for (int hi = 0; hi < 4; ++hi) {
                    acc[ni][hi] += fa[ni].x * wr[hi].x + fa[ni].y * wr[hi].y
                                 + fa[ni].z * wr[hi].z + fa[ni].w * wr[hi].w
                                 + fx[ni].x * wo[hi].x + fx[ni].y * wo[hi].y
                                 + fx[ni].z * wo[hi].z + fx[ni].w * wo[hi].w;
                }
        }
    }

    __syncthreads();
    #pragma unroll
    for (int hi = 0; hi < 4; ++hi) {
        float b = brel[th + 32 * hi];
        #pragma unroll
        for (int ni = 0; ni < 4; ++ni)
            smA[tn + 8 * ni][th + 32 * hi] = lrelu(acc[ni][hi] + b);
    }

    float acc2[4][4];
    #pragma unroll
    for (int i = 0; i < 4; ++i)
        #pragma unroll
        for (int j = 0; j < 4; ++j) acc2[i][j] = 0.f;

    for (int kc = 0; kc < HCH; kc += KC) {
        __syncthreads();
        #pragma unroll
        for (int i = 0; i < 8; ++i) {
            int e = tid + i * 256;
            int row = e >> 4, col = e & 15;
            smW0[row][col] = Wlin[row * 128 + kc + col];
        }
        __syncthreads();
        #pragma unroll
        for (int kq = 0; kq < KC / 4; ++kq) {
            float4 wl[4], f2[4];
            #pragma unroll
            for (int hi = 0; hi < 4; ++hi)
                wl[hi] = *(const float4*)&smW0[th + 32 * hi][kq * 4];
            #pragma unroll
            for (int ni = 0; ni < 4; ++ni)
                f2[ni] = *(const float4*)&smA[tn + 8 * ni][kc + kq * 4];
            #pragma unroll
            for (int ni = 0; ni < 4; ++ni)
                #pragma unroll
                for (int hi = 0; hi < 4; ++hi)
                    acc2[ni][hi] += f2[ni].x * wl[hi].x + f2[ni].y * wl[hi].y
                                  + f2[ni].z * wl[hi].z + f2[ni].w * wl[hi].w;
        }
    }

    __syncthreads();
    bool valid[4];
    #pragma unroll
    for (int ni = 0; ni < 4; ++ni) valid[ni] = (n0 + tn + 8 * ni) < NNODES;

    #pragma unroll
    for (int hi = 0; hi < 4; ++hi) {
        float b = blin[th + 32 * hi];
        float ps = 0.f, pq = 0.f;
        #pragma unroll
        for (int ni = 0; ni < 4; ++ni) {
            float v = acc2[ni][hi] + b;
            smX[tn + 8 * ni][th + 32 * hi] = v;
            if (valid[ni]) { ps += v; pq += v * v; }
        }
        ps += __shfl_xor(ps, 1); ps += __shfl_xor(ps, 2); ps += __shfl_xor(ps, 4);
        pq += __shfl_xor(pq, 1); pq += __shfl_xor(pq, 2); pq += __shfl_xor(pq, 4);
        if (tn == 0) {
            atomicAdd(&sums[th + 32 * hi], ps);
            atomicAdd(&sumsq[th + 32 * hi], pq);
        }
    }
    __syncthreads();

    #pragma unroll
    for (int i = 0; i < 4; ++i) {
        int e = tid + i * 256;
        int n = e >> 5, kq = e & 31;
        if (n0 + n < NNODES)
            ((float4*)x3out)[(long)(n0 + n) * 32 + kq] = *(const float4*)&smX[n][kq * 4];
    }
}

// ---------------- BN finalize ----------------
__global__ void bn_final_kernel(const float* __restrict__ sums, const float* __restrict__ sumsq,
                                const float* __restrict__ gamma, const float* __restrict__ beta,
                                float* __restrict__ ss)
{
    int h = threadIdx.x;
    float mean = sums[h] * (1.f / NNODES);
    float var = sumsq[h] * (1.f / NNODES) - mean * mean;
    float sc = gamma[h] * rsqrtf(var + BN_EPS);
    ss[h] = sc;
    ss[128 + h] = beta[h] - mean * sc;
}

// ---------------- BN apply + leaky ----------------
__global__ __launch_bounds__(256)
void bn_apply_kernel(float* __restrict__ out, const float* __restrict__ ss)
{
    __shared__ float s_sc[128], s_sh[128];
    if (threadIdx.x < 128) {
        s_sc[threadIdx.x] = ss[threadIdx.x];
        s_sh[threadIdx.x] = ss[128 + threadIdx.x];
    }
    __syncthreads();
    const int total = NNODES * 32;
    float4* o4 = (float4*)out;
    for (int i = blockIdx.x * 256 + threadIdx.x; i < total; i += gridDim.x * 256) {
        float4 v = o4[i];
        int h = (i & 31) * 4;
        v.x = lrelu(v.x * s_sc[h + 0] + s_sh[h + 0]);
        v.y = lrelu(v.y * s_sc[h + 1] + s_sh[h + 1]);
        v.z = lrelu(v.z * s_sc[h + 2] + s_sh[h + 2]);
        v.w = lrelu(v.w * s_sc[h + 3] + s_sh[h + 3]);
        o4[i] = v;
    }
}

extern "C" void kernel_launch(void* const* d_in, const int* in_sizes, int n_in,
                              void* d_out, int out_size, void* d_ws, size_t ws_size,
                              hipStream_t stream)
{
    const float* x     = (const float*)d_in[0];
    const int*   ei    = (const int*)d_in[1];
    const float* Wrel  = (const float*)d_in[3];
    const float* brel  = (const float*)d_in[4];
    const float* Wroot = (const float*)d_in[5];
    const float* Wlin  = (const float*)d_in[6];
    const float* blin  = (const float*)d_in[7];
    const float* gamma = (const float*)d_in[8];
    const float* beta  = (const float*)d_in[9];
    float* out = (float*)d_out;

    const int n_edges = in_sizes[1] / 2;
    const int* src = ei;
    const int* dst = ei + n_edges;

    // workspace layout (bytes):
    // [0, 25.6e6)            agg (fully written by gather — no zeroing)
    // [25.6e6, +200000)      cnt        } zeroed together
    // [25.8e6, +2048)        stats ss   }
    // then offs (NNODES+1 ints), cur (NNODES ints), esrc (n_edges ints)
    char* ws = (char*)d_ws;
    float* agg   = (float*)ws;
    int*   cnt   = (int*)(ws + 25600000);
    float* sums  = (float*)(ws + 25800000);
    float* sumsq = sums + 128;
    float* ss    = sums + 256;
    int*   offs  = (int*)(ws + 25802048);
    int*   cur   = (int*)(ws + 26002064);
    int*   esrc  = (int*)(ws + 26202064);

    hipMemsetAsync(cnt, 0, 202048, stream);   // cnt + stats

    hist_kernel<<<2048, 256, 0, stream>>>(dst, cnt, n_edges);
    scan_kernel<<<1, 256, 0, stream>>>(cnt, offs, cur);
    bucket_kernel<<<2048, 256, 0, stream>>>(src, dst, cur, esrc, n_edges);
    gather_kernel<<<(NNODES + 7) / 8, 256, 0, stream>>>(
        (const float4*)x, esrc, offs, (float4*)agg);

    fused_mlp_kernel<<<(NNODES + NB - 1) / NB, 256, 0, stream>>>(
        agg, x, Wrel, brel, Wroot, Wlin, blin, out, sums, sumsq);

    bn_final_kernel<<<1, 128, 0, stream>>>(sums, sumsq, gamma, beta, ss);

    bn_apply_kernel<<<2048, 256, 0, stream>>>(out, ss);
}

// Round 3
// 460.535 us; speedup vs baseline: 6.2083x; 1.2859x over previous
//
#include <hip/hip_runtime.h>

#define NNODES 50000
#define NEG 0.01f
#define BN_EPS 1e-5f

typedef __attribute__((ext_vector_type(8))) short bf16x8;
typedef __attribute__((ext_vector_type(4))) float f32x4;

__device__ __forceinline__ float lrelu(float v) { return v >= 0.f ? v : NEG * v; }
__device__ __forceinline__ float bf_lo(unsigned u) { return __uint_as_float(u << 16); }
__device__ __forceinline__ float bf_hi(unsigned u) { return __uint_as_float(u & 0xffff0000u); }
__device__ __forceinline__ unsigned f2bf(float x) {          // RNE, 16-bit result
    unsigned u = __float_as_uint(x);
    return (u + 0x7fffu + ((u >> 16) & 1u)) >> 16;
}
__device__ __forceinline__ unsigned packbf(float lo, float hi) {
    unsigned b = __float_as_uint(hi);
    b = (b + 0x7fffu + ((b >> 16) & 1u)) & 0xffff0000u;
    return (f2bf(lo) & 0xffffu) | b;
}

// ---------------- 0. convert x + weights to bf16 ----------------
__global__ __launch_bounds__(256)
void prep_kernel(const float* __restrict__ x, const float* __restrict__ Wrel,
                 const float* __restrict__ Wroot, const float* __restrict__ Wlin,
                 unsigned* __restrict__ xb2, unsigned* __restrict__ wb2)
{
    const int NPX = 3200000;           // float pairs in x
    const int NPW = 24576;             // float pairs in 3 weight mats
    for (int i = blockIdx.x * 256 + threadIdx.x; i < NPX + NPW; i += gridDim.x * 256) {
        if (i < NPX) {
            float2 v = ((const float2*)x)[i];
            xb2[i] = packbf(v.x, v.y);
        } else {
            int j = i - NPX;
            const float* W = (j < 8192) ? Wrel : (j < 16384 ? Wroot : Wlin);
            float2 v = ((const float2*)W)[j & 8191];
            wb2[j] = packbf(v.x, v.y);
        }
    }
}

// ---------------- 1. histogram ----------------
__global__ __launch_bounds__(256)
void hist_kernel(const int* __restrict__ dst, int* __restrict__ cnt, int n_edges)
{
    for (int i = blockIdx.x * 256 + threadIdx.x; i < n_edges; i += gridDim.x * 256)
        atomicAdd(&cnt[dst[i]], 1);
}

// ---------------- 2. exclusive scan (1 block, 1024 thr) ----------------
__global__ __launch_bounds__(1024)
void scan_kernel(const int* __restrict__ cnt, int* __restrict__ offs, int* __restrict__ cur)
{
    __shared__ int wsum[16];
    const int t = threadIdx.x;
    const int per = (NNODES + 1023) / 1024;            // 49
    const int begin = t * per;
    const int end = min(begin + per, NNODES);

    int s = 0;
    for (int i = begin; i < end; ++i) s += cnt[i];

    const int lane = t & 63, w = t >> 6;
    int v = s;
    #pragma unroll
    for (int d = 1; d < 64; d <<= 1) {
        int u = __shfl_up(v, d);
        if (lane >= d) v += u;
    }
    if (lane == 63) wsum[w] = v;
    __syncthreads();
    int woff = 0;
    for (int i = 0; i < w; ++i) woff += wsum[i];
    int run = woff + v - s;

    for (int i = begin; i < end; ++i) {
        offs[i] = run; cur[i] = run;
        run += cnt[i];
    }
    if (t == 1023) offs[NNODES] = run;
}

// ---------------- 3. bucket edges by dst (ushort src ids) ----------------
__global__ __launch_bounds__(256)
void bucket_kernel(const int* __restrict__ src, const int* __restrict__ dst,
                   int* __restrict__ cur, unsigned short* __restrict__ esrc, int n_edges)
{
    for (int i = blockIdx.x * 256 + threadIdx.x; i < n_edges; i += gridDim.x * 256) {
        int p = atomicAdd(&cur[dst[i]], 1);
        esrc[p] = (unsigned short)src[i];
    }
}

// ---------------- 4. gather-accumulate (1 wave per node) ----------------
__global__ __launch_bounds__(256)
void gather_kernel(const unsigned short* __restrict__ xb, const unsigned short* __restrict__ esrc,
                   const int* __restrict__ offs, unsigned short* __restrict__ aggb)
{
    const int g = blockIdx.x * 4 + (threadIdx.x >> 6);   // node (4 per block)
    const int l = threadIdx.x & 63;
    const int kg = l >> 4;                               // edge sub-slot 0..3
    const int c = l & 15;                                // 16B chunk in 256B row
    if (g >= NNODES) return;
    const int b = offs[g], e = offs[g + 1];

    float a0=0,a1=0,a2=0,a3=0,a4=0,a5=0,a6=0,a7=0;
    for (int i = b + kg; i < e; i += 4) {
        int s = esrc[i];
        uint4 v = *(const uint4*)(xb + (long)s * 128 + c * 8);
        a0 += bf_lo(v.x); a1 += bf_hi(v.x);
        a2 += bf_lo(v.y); a3 += bf_hi(v.y);
        a4 += bf_lo(v.z); a5 += bf_hi(v.z);
        a6 += bf_lo(v.w); a7 += bf_hi(v.w);
    }
    // reduce over the 4 kg slots (lanes xor 16, 32)
    a0 += __shfl_xor(a0,16); a0 += __shfl_xor(a0,32);
    a1 += __shfl_xor(a1,16); a1 += __shfl_xor(a1,32);
    a2 += __shfl_xor(a2,16); a2 += __shfl_xor(a2,32);
    a3 += __shfl_xor(a3,16); a3 += __shfl_xor(a3,32);
    a4 += __shfl_xor(a4,16); a4 += __shfl_xor(a4,32);
    a5 += __shfl_xor(a5,16); a5 += __shfl_xor(a5,32);
    a6 += __shfl_xor(a6,16); a6 += __shfl_xor(a6,32);
    a7 += __shfl_xor(a7,16); a7 += __shfl_xor(a7,32);
    if (kg == 0) {
        uint4 o;
        o.x = packbf(a0,a1); o.y = packbf(a2,a3);
        o.z = packbf(a4,a5); o.w = packbf(a6,a7);
        *(uint4*)(aggb + (long)g * 128 + c * 8) = o;
    }
}

// ---------------- 5. MFMA MLP: x3 = Wlin(lrelu([agg,x]@[Wrel,Wroot]^T+brel))+blin ----------------
// block = 256 thr = 4 waves; 32 nodes/block; wave w owns output cols [w*32, w*32+32)
__global__ __launch_bounds__(256)
void mlp_mfma_kernel(const unsigned short* __restrict__ aggb, const unsigned short* __restrict__ xb,
                     const unsigned short* __restrict__ wb,
                     const float* __restrict__ brel, const float* __restrict__ blin,
                     float* __restrict__ out, float* __restrict__ sums, float* __restrict__ sumsq)
{
    __shared__ unsigned short smx2[32][136];   // x2 staging, pitch 136 (272B: 2-way banks)

    const int tid = threadIdx.x;
    const int w = tid >> 6;
    const int l = tid & 63;
    const int l15 = l & 15;
    const int kg = l >> 4;
    const int n0 = blockIdx.x * 32;

    const unsigned short* Wrelb  = wb;
    const unsigned short* Wrootb = wb + 16384;
    const unsigned short* Wlinb  = wb + 32768;

    const int rA0 = n0 + l15, rA1 = n0 + 16 + l15;
    const long cA0 = min(rA0, NNODES - 1), cA1 = min(rA1, NNODES - 1);
    const int rB0 = w * 32 + l15, rB1 = rB0 + 16;   // also = output cols

    f32x4 acc00 = {0.f,0.f,0.f,0.f}, acc01 = acc00, acc10 = acc00, acc11 = acc00;

    // stage 1: K=256 over [aggb | xb] x [Wrel | Wroot]
    #pragma unroll
    for (int s = 0; s < 8; ++s) {
        const unsigned short* Ab = (s < 4) ? aggb : xb;
        const unsigned short* Bb = (s < 4) ? Wrelb : Wrootb;
        const int ko = (s & 3) * 32 + kg * 8;
        bf16x8 a0 = *(const bf16x8*)(Ab + cA0 * 128 + ko);
        bf16x8 a1 = *(const bf16x8*)(Ab + cA1 * 128 + ko);
        bf16x8 b0 = *(const bf16x8*)(Bb + rB0 * 128 + ko);
        bf16x8 b1 = *(const bf16x8*)(Bb + rB1 * 128 + ko);
        acc00 = __builtin_amdgcn_mfma_f32_16x16x32_bf16(a0, b0, acc00, 0, 0, 0);
        acc01 = __builtin_amdgcn_mfma_f32_16x16x32_bf16(a0, b1, acc01, 0, 0, 0);
        acc10 = __builtin_amdgcn_mfma_f32_16x16x32_bf16(a1, b0, acc10, 0, 0, 0);
        acc11 = __builtin_amdgcn_mfma_f32_16x16x32_bf16(a1, b1, acc11, 0, 0, 0);
    }

    // x2 = lrelu(x1 + brel) -> LDS bf16 (D layout: row=(kg*4+r), col=l15 per tile)
    {
        const float br0 = brel[rB0], br1 = brel[rB1];
        const int mr = kg * 4;
        #pragma unroll
        for (int r = 0; r < 4; ++r) {
            smx2[mr + r][rB0]      = (unsigned short)f2bf(lrelu(acc00[r] + br0));
            smx2[mr + r][rB1]      = (unsigned short)f2bf(lrelu(acc01[r] + br1));
            smx2[16 + mr + r][rB0] = (unsigned short)f2bf(lrelu(acc10[r] + br0));
            smx2[16 + mr + r][rB1] = (unsigned short)f2bf(lrelu(acc11[r] + br1));
        }
    }
    __syncthreads();

    // stage 2: K=128, A from LDS, B = Wlin
    f32x4 o00 = {0.f,0.f,0.f,0.f}, o01 = o00, o10 = o00, o11 = o00;
    #pragma unroll
    for (int s = 0; s < 4; ++s) {
        const int ko = s * 32 + kg * 8;
        bf16x8 a0 = *(const bf16x8*)(&smx2[l15][ko]);
        bf16x8 a1 = *(const bf16x8*)(&smx2[16 + l15][ko]);
        bf16x8 b0 = *(const bf16x8*)(Wlinb + rB0 * 128 + ko);
        bf16x8 b1 = *(const bf16x8*)(Wlinb + rB1 * 128 + ko);
        o00 = __builtin_amdgcn_mfma_f32_16x16x32_bf16(a0, b0, o00, 0, 0, 0);
        o01 = __builtin_amdgcn_mfma_f32_16x16x32_bf16(a0, b1, o01, 0, 0, 0);
        o10 = __builtin_amdgcn_mfma_f32_16x16x32_bf16(a1, b0, o10, 0, 0, 0);
        o11 = __builtin_amdgcn_mfma_f32_16x16x32_bf16(a1, b1, o11, 0, 0, 0);
    }

    // epilogue: +blin, store x3 fp32, BN partial sums
    const float bl0 = blin[rB0], bl1 = blin[rB1];
    float ps0 = 0.f, pq0 = 0.f, ps1 = 0.f, pq1 = 0.f;
    const int mr = kg * 4;
    #pragma unroll
    for (int mi = 0; mi < 2; ++mi) {
        f32x4 v0 = mi ? o10 : o00;
        f32x4 v1 = mi ? o11 : o01;
        #pragma unroll
        for (int r = 0; r < 4; ++r) {
            int m = n0 + mi * 16 + mr + r;
            if (m < NNODES) {
                float y0 = v0[r] + bl0;
                float y1 = v1[r] + bl1;
                out[(long)m * 128 + rB0] = y0;
                out[(long)m * 128 + rB1] = y1;
                ps0 += y0; pq0 += y0 * y0;
                ps1 += y1; pq1 += y1 * y1;
            }
        }
    }
    ps0 += __shfl_xor(ps0, 16); ps0 += __shfl_xor(ps0, 32);
    pq0 += __shfl_xor(pq0, 16); pq0 += __shfl_xor(pq0, 32);
    ps1 += __shfl_xor(ps1, 16); ps1 += __shfl_xor(ps1, 32);
    pq1 += __shfl_xor(pq1, 16); pq1 += __shfl_xor(pq1, 32);
    if (kg == 0) {
        atomicAdd(&sums[rB0], ps0);  atomicAdd(&sumsq[rB0], pq0);
        atomicAdd(&sums[rB1], ps1);  atomicAdd(&sumsq[rB1], pq1);
    }
}

// ---------------- 6. BN finalize ----------------
__global__ void bn_final_kernel(const float* __restrict__ sums, const float* __restrict__ sumsq,
                                const float* __restrict__ gamma, const float* __restrict__ beta,
                                float* __restrict__ ss)
{
    int h = threadIdx.x;
    float mean = sums[h] * (1.f / NNODES);
    float var = sumsq[h] * (1.f / NNODES) - mean * mean;
    float sc = gamma[h] * rsqrtf(var + BN_EPS);
    ss[h] = sc;
    ss[128 + h] = beta[h] - mean * sc;
}

// ---------------- 7. BN apply + leaky (in-place fp32) ----------------
__global__ __launch_bounds__(256)
void bn_apply_kernel(float* __restrict__ out, const float* __restrict__ ss)
{
    __shared__ float s_sc[128], s_sh[128];
    if (threadIdx.x < 128) {
        s_sc[threadIdx.x] = ss[threadIdx.x];
        s_sh[threadIdx.x] = ss[128 + threadIdx.x];
    }
    __syncthreads();
    const int total = NNODES * 32;
    float4* o4 = (float4*)out;
    for (int i = blockIdx.x * 256 + threadIdx.x; i < total; i += gridDim.x * 256) {
        float4 v = o4[i];
        int h = (i & 31) * 4;
        v.x = lrelu(v.x * s_sc[h + 0] + s_sh[h + 0]);
        v.y = lrelu(v.y * s_sc[h + 1] + s_sh[h + 1]);
        v.z = lrelu(v.z * s_sc[h + 2] + s_sh[h + 2]);
        v.w = lrelu(v.w * s_sc[h + 3] + s_sh[h + 3]);
        o4[i] = v;
    }
}

extern "C" void kernel_launch(void* const* d_in, const int* in_sizes, int n_in,
                              void* d_out, int out_size, void* d_ws, size_t ws_size,
                              hipStream_t stream)
{
    const float* x     = (const float*)d_in[0];
    const int*   ei    = (const int*)d_in[1];
    const float* Wrel  = (const float*)d_in[3];
    const float* brel  = (const float*)d_in[4];
    const float* Wroot = (const float*)d_in[5];
    const float* Wlin  = (const float*)d_in[6];
    const float* blin  = (const float*)d_in[7];
    const float* gamma = (const float*)d_in[8];
    const float* beta  = (const float*)d_in[9];
    float* out = (float*)d_out;

    const int n_edges = in_sizes[1] / 2;
    const int* src = ei;
    const int* dst = ei + n_edges;

    // workspace layout (bytes):
    // xb    @ 0          : 12,800,000  (x as bf16)
    // aggb  @ 12,800,000 : 12,800,000  (agg as bf16)
    // wb    @ 25,600,000 : 98,304      (Wrel|Wroot|Wlin bf16)
    // cnt   @ 25,700,000 : 200,000     } memset together
    // stats @ 25,900,000 : 2,048       }
    // offs  @ 25,902,048 : 200,004
    // cur   @ 26,102,052 : 200,000
    // esrc  @ 26,302,052 : 3,200,000   (ushort)  -> total 29.5 MB
    char* ws = (char*)d_ws;
    unsigned short* xb   = (unsigned short*)ws;
    unsigned short* aggb = (unsigned short*)(ws + 12800000);
    unsigned short* wb   = (unsigned short*)(ws + 25600000);
    int*   cnt   = (int*)(ws + 25700000);
    float* sums  = (float*)(ws + 25900000);
    float* sumsq = sums + 128;
    float* ss    = sums + 256;
    int*   offs  = (int*)(ws + 25902048);
    int*   cur   = (int*)(ws + 26102052);
    unsigned short* esrc = (unsigned short*)(ws + 26302052);

    hipMemsetAsync(cnt, 0, 202048, stream);   // cnt + stats

    prep_kernel<<<4096, 256, 0, stream>>>(x, Wrel, Wroot, Wlin, (unsigned*)xb, (unsigned*)wb);
    hist_kernel<<<2048, 256, 0, stream>>>(dst, cnt, n_edges);
    scan_kernel<<<1, 1024, 0, stream>>>(cnt, offs, cur);
    bucket_kernel<<<2048, 256, 0, stream>>>(src, dst, cur, esrc, n_edges);
    gather_kernel<<<(NNODES + 3) / 4, 256, 0, stream>>>(xb, esrc, offs, aggb);
    mlp_mfma_kernel<<<(NNODES + 31) / 32, 256, 0, stream>>>(
        aggb, xb, wb, brel, blin, out, sums, sumsq);
    bn_final_kernel<<<1, 128, 0, stream>>>(sums, sumsq, gamma, beta, ss);
    bn_apply_kernel<<<2048, 256, 0, stream>>>(out, ss);
}